// Round 1
// baseline (3742.197 us; speedup 1.0000x reference)
//
#include <hip/hip_runtime.h>

// Residual VQ, bit-exact replication of the numpy reference's fp32 rounding.
// B=16 S=2048 D=64 K=8 M=2048.
//
// Numerics contract (verified bit-exact previously, absmax 0.0):
//  - r2/c2: numpy pairwise_sum 8-accumulator order, no FMA contraction
//  - cross: numpy einsum baseline-SSE order: 4 chains (d mod 4), per 16-block
//           groups at offsets {12,8,4,0}+j, blocks ascending, hsum (L0+L1)+(L2+L3)
//  - t = fl(r2 - 2*cross) via fma(-2,cross,r2); d2 = fl(t + c2)
//  - argmin: first occurrence (strict <; cross-chunk combine ascending-m)
//
// R6 (this round): the m-loop's SMEM row fetch (s_load_dwordx16 + lgkmcnt(0)
// per row) serialized on K$-miss latency -> 28% VALU idle. SMEM can return
// out-of-order (only lgkmcnt(0) is safe) and the ~102-SGPR ceiling forbids
// double buffering, so the row+c2 stream moves to wave-uniform VMEM
// (global_load_dwordx4 broadcast) with VGPR ping-pong buffers and counted
// in-order s_waitcnt vmcnt(17): one full row-pair of prefetch lead.
// Arithmetic sequence is unchanged (same ops, same order, same bits; codebook
// values arrive in broadcast VGPRs instead of SGPRs).
// VGPRs: residual v[16:79], scratch v[80:95], bufA v[96:160], bufB v[164:228]
// -> 229 VGPRs, 2 waves/SIMD, WPB=4 (512 rows/wave), grid exactly resident.

#define BB 16
#define SS 2048
#define DD 64
#define KK 8
#define MM 2048
#define NPTS (BB * SS)      // 32768
#define QSIZE (NPTS * DD)   // 2097152
#define WPB 4               // waves per block
#define MCHUNK (MM / WPB)   // 512 m per wave

// ---- prep: c2[k][m] (numpy pairwise) ----
__global__ __launch_bounds__(256) void rvq_prep(const float* __restrict__ cb,
                                                float* __restrict__ c2) {
#pragma clang fp contract(off)
    int tid = blockIdx.x * 256 + threadIdx.x;  // 0 .. K*M-1
    const float* row = cb + (size_t)tid * DD;
    float r[8];
#pragma unroll
    for (int j = 0; j < 8; ++j) { float v = row[j]; r[j] = v * v; }
#pragma unroll
    for (int i = 8; i < DD; i += 8) {
#pragma unroll
        for (int j = 0; j < 8; ++j) { float v = row[i + j]; float t = v * v; r[j] += t; }
    }
    c2[tid] = ((r[0] + r[1]) + (r[2] + r[3])) + ((r[4] + r[5]) + (r[6] + r[7]));
}

// r2 chain block for k-th 8-float group
#define R2K(A, B, C, E) \
    "v_pk_mul_f32 v[92:93], v[" A "], v[" A "]\n\t" \
    "v_pk_add_f32 v[80:81], v[80:81], v[92:93]\n\t" \
    "v_pk_mul_f32 v[92:93], v[" B "], v[" B "]\n\t" \
    "v_pk_add_f32 v[82:83], v[82:83], v[92:93]\n\t" \
    "v_pk_mul_f32 v[92:93], v[" C "], v[" C "]\n\t" \
    "v_pk_add_f32 v[84:85], v[84:85], v[92:93]\n\t" \
    "v_pk_mul_f32 v[92:93], v[" E "], v[" E "]\n\t" \
    "v_pk_add_f32 v[86:87], v[86:87], v[92:93]\n\t"

// einsum group: codebook v-pairs (CA, CB), residual v-pairs (RA, RB)
#define GRPV(CA, CB, RA, RB) \
    "v_pk_mul_f32 v[84:85], v[" CA "], v[" RA "]\n\t" \
    "v_pk_mul_f32 v[86:87], v[" CB "], v[" RB "]\n\t" \
    "v_pk_add_f32 v[80:81], v[80:81], v[84:85]\n\t" \
    "v_pk_add_f32 v[82:83], v[82:83], v[86:87]\n\t"

// 16 row loads + 1 c2 load into buffer A (v[96:159], c2 -> v160)
#define LDA \
    "global_load_dwordx4 v[96:99],   v94, %[cb]\n\t"            \
    "global_load_dwordx4 v[100:103], v94, %[cb] offset:16\n\t"  \
    "global_load_dwordx4 v[104:107], v94, %[cb] offset:32\n\t"  \
    "global_load_dwordx4 v[108:111], v94, %[cb] offset:48\n\t"  \
    "global_load_dwordx4 v[112:115], v94, %[cb] offset:64\n\t"  \
    "global_load_dwordx4 v[116:119], v94, %[cb] offset:80\n\t"  \
    "global_load_dwordx4 v[120:123], v94, %[cb] offset:96\n\t"  \
    "global_load_dwordx4 v[124:127], v94, %[cb] offset:112\n\t" \
    "global_load_dwordx4 v[128:131], v94, %[cb] offset:128\n\t" \
    "global_load_dwordx4 v[132:135], v94, %[cb] offset:144\n\t" \
    "global_load_dwordx4 v[136:139], v94, %[cb] offset:160\n\t" \
    "global_load_dwordx4 v[140:143], v94, %[cb] offset:176\n\t" \
    "global_load_dwordx4 v[144:147], v94, %[cb] offset:192\n\t" \
    "global_load_dwordx4 v[148:151], v94, %[cb] offset:208\n\t" \
    "global_load_dwordx4 v[152:155], v94, %[cb] offset:224\n\t" \
    "global_load_dwordx4 v[156:159], v94, %[cb] offset:240\n\t" \
    "global_load_dword   v160,       v95, %[c2]\n\t"

// buffer B (v[164:227], c2 -> v228): next row, +256 B / +4 B
#define LDB \
    "global_load_dwordx4 v[164:167], v94, %[cb] offset:256\n\t" \
    "global_load_dwordx4 v[168:171], v94, %[cb] offset:272\n\t" \
    "global_load_dwordx4 v[172:175], v94, %[cb] offset:288\n\t" \
    "global_load_dwordx4 v[176:179], v94, %[cb] offset:304\n\t" \
    "global_load_dwordx4 v[180:183], v94, %[cb] offset:320\n\t" \
    "global_load_dwordx4 v[184:187], v94, %[cb] offset:336\n\t" \
    "global_load_dwordx4 v[188:191], v94, %[cb] offset:352\n\t" \
    "global_load_dwordx4 v[192:195], v94, %[cb] offset:368\n\t" \
    "global_load_dwordx4 v[196:199], v94, %[cb] offset:384\n\t" \
    "global_load_dwordx4 v[200:203], v94, %[cb] offset:400\n\t" \
    "global_load_dwordx4 v[204:207], v94, %[cb] offset:416\n\t" \
    "global_load_dwordx4 v[208:211], v94, %[cb] offset:432\n\t" \
    "global_load_dwordx4 v[212:215], v94, %[cb] offset:448\n\t" \
    "global_load_dwordx4 v[216:219], v94, %[cb] offset:464\n\t" \
    "global_load_dwordx4 v[220:223], v94, %[cb] offset:480\n\t" \
    "global_load_dwordx4 v[224:227], v94, %[cb] offset:496\n\t" \
    "global_load_dword   v228,       v95, %[c2] offset:4\n\t"

// einsum from buffer A: row d -> v[96+d]; blocks ascending, groups {12,8,4,0}+b
#define EINA \
    "v_pk_mul_f32 v[80:81], v[108:109], v[28:29]\n\t" \
    "v_pk_mul_f32 v[82:83], v[110:111], v[30:31]\n\t" \
    GRPV("104:105","106:107","24:25","26:27") \
    GRPV("100:101","102:103","20:21","22:23") \
    GRPV("96:97","98:99","16:17","18:19") \
    GRPV("124:125","126:127","44:45","46:47") \
    GRPV("120:121","122:123","40:41","42:43") \
    GRPV("116:117","118:119","36:37","38:39") \
    GRPV("112:113","114:115","32:33","34:35") \
    GRPV("140:141","142:143","60:61","62:63") \
    GRPV("136:137","138:139","56:57","58:59") \
    GRPV("132:133","134:135","52:53","54:55") \
    GRPV("128:129","130:131","48:49","50:51") \
    GRPV("156:157","158:159","76:77","78:79") \
    GRPV("152:153","154:155","72:73","74:75") \
    GRPV("148:149","150:151","68:69","70:71") \
    GRPV("144:145","146:147","64:65","66:67")

// einsum from buffer B: row d -> v[164+d]
#define EINB \
    "v_pk_mul_f32 v[80:81], v[176:177], v[28:29]\n\t" \
    "v_pk_mul_f32 v[82:83], v[178:179], v[30:31]\n\t" \
    GRPV("172:173","174:175","24:25","26:27") \
    GRPV("168:169","170:171","20:21","22:23") \
    GRPV("164:165","166:167","16:17","18:19") \
    GRPV("192:193","194:195","44:45","46:47") \
    GRPV("188:189","190:191","40:41","42:43") \
    GRPV("184:185","186:187","36:37","38:39") \
    GRPV("180:181","182:183","32:33","34:35") \
    GRPV("208:209","210:211","60:61","62:63") \
    GRPV("204:205","206:207","56:57","58:59") \
    GRPV("200:201","202:203","52:53","54:55") \
    GRPV("196:197","198:199","48:49","50:51") \
    GRPV("224:225","226:227","76:77","78:79") \
    GRPV("220:221","222:223","72:73","74:75") \
    GRPV("216:217","218:219","68:69","70:71") \
    GRPV("212:213","214:215","64:65","66:67")

// hsum, d2, argmin update; C2 = c2 register number (string)
#define FIN(C2) \
    "v_add_f32 v92, v80, v81\n\t" \
    "v_add_f32 v93, v82, v83\n\t" \
    "v_add_f32 v92, v92, v93\n\t" \
    "v_fma_f32 v92, v92, -2.0, v88\n\t" \
    "v_add_f32 v92, v" C2 ", v92\n\t" \
    "v_cmp_lt_f32 vcc, v92, v89\n\t" \
    "v_cndmask_b32 v89, v89, v92, vcc\n\t" \
    "v_cndmask_b32 v90, v90, v91, vcc\n\t" \
    "v_add_u32 v91, 1, v91\n\t"

// ---- one RVQ step ----
// grid = NPTS/64 = 512 blocks x 256 threads (4 waves, 512 m each).
__global__ __launch_bounds__(256, 2) void rvq_step(const float* __restrict__ res_in,
                                                   float* __restrict__ res_out,
                                                   const float* __restrict__ cbk,  // (M,D)
                                                   const float* __restrict__ c2k,  // (M,)
                                                   float* __restrict__ idx_out) {  // (NPTS,)
#pragma clang fp contract(off)
    const int tid = threadIdx.x;
    const int lane = tid & 63;
    const int wv = __builtin_amdgcn_readfirstlane(tid >> 6);  // wave-uniform
    const int point = blockIdx.x * 64 + lane;

    const int m0 = wv * MCHUNK;
    const float* cbw = cbk + (size_t)m0 * DD;   // this wave's chunk base
    const float* c2w = c2k + m0;
    const unsigned long long ra = (unsigned long long)(res_in + (size_t)point * DD);

    float best;
    int bidx;
    asm volatile(
        // ---- residual: 64 floats -> v[16:79] ----
        "global_load_dwordx4 v[16:19], %[ra], off\n\t"
        "global_load_dwordx4 v[20:23], %[ra], off offset:16\n\t"
        "global_load_dwordx4 v[24:27], %[ra], off offset:32\n\t"
        "global_load_dwordx4 v[28:31], %[ra], off offset:48\n\t"
        "global_load_dwordx4 v[32:35], %[ra], off offset:64\n\t"
        "global_load_dwordx4 v[36:39], %[ra], off offset:80\n\t"
        "global_load_dwordx4 v[40:43], %[ra], off offset:96\n\t"
        "global_load_dwordx4 v[44:47], %[ra], off offset:112\n\t"
        "global_load_dwordx4 v[48:51], %[ra], off offset:128\n\t"
        "global_load_dwordx4 v[52:55], %[ra], off offset:144\n\t"
        "global_load_dwordx4 v[56:59], %[ra], off offset:160\n\t"
        "global_load_dwordx4 v[60:63], %[ra], off offset:176\n\t"
        "global_load_dwordx4 v[64:67], %[ra], off offset:192\n\t"
        "global_load_dwordx4 v[68:71], %[ra], off offset:208\n\t"
        "global_load_dwordx4 v[72:75], %[ra], off offset:224\n\t"
        "global_load_dwordx4 v[76:79], %[ra], off offset:240\n\t"
        "s_waitcnt vmcnt(0)\n\t"
        // ---- r2, numpy pairwise 8-acc order; accs in v[80:87] ----
        "v_pk_mul_f32 v[80:81], v[16:17], v[16:17]\n\t"
        "v_pk_mul_f32 v[82:83], v[18:19], v[18:19]\n\t"
        "v_pk_mul_f32 v[84:85], v[20:21], v[20:21]\n\t"
        "v_pk_mul_f32 v[86:87], v[22:23], v[22:23]\n\t"
        R2K("24:25", "26:27", "28:29", "30:31")
        R2K("32:33", "34:35", "36:37", "38:39")
        R2K("40:41", "42:43", "44:45", "46:47")
        R2K("48:49", "50:51", "52:53", "54:55")
        R2K("56:57", "58:59", "60:61", "62:63")
        R2K("64:65", "66:67", "68:69", "70:71")
        R2K("72:73", "74:75", "76:77", "78:79")
        "v_add_f32 v92, v80, v81\n\t"
        "v_add_f32 v93, v82, v83\n\t"
        "v_add_f32 v92, v92, v93\n\t"
        "v_add_f32 v93, v84, v85\n\t"
        "v_add_f32 v88, v86, v87\n\t"
        "v_add_f32 v93, v93, v88\n\t"
        "v_add_f32 v88, v92, v93\n\t"          // r2 -> v88
        // ---- init ----
        "v_mov_b32 v89, 0x7f800000\n\t"        // best = +inf
        "v_mov_b32 v90, 0\n\t"                 // bidx = 0
        "v_mov_b32 v91, %[m0]\n\t"             // current m
        // ---- prime ping-pong: rows 0,1 in flight ----
        "v_mov_b32 v94, 0\n\t"                 // row byte offset (pair base)
        "v_mov_b32 v95, 0\n\t"                 // c2 byte offset (pair base)
        LDA
        LDB
        "v_mov_b32 v94, 0x200\n\t"             // next pair base
        "v_mov_b32 v95, 8\n\t"
        "s_mov_b32 s29, 0\n\t"                 // pair counter
        "Lrvq_%=:\n\t"
        // ---- row A: wait its 17 loads (B's 17 stay in flight) ----
        "s_waitcnt vmcnt(17)\n\t"
        EINA
        FIN("160")
        LDA                                    // refill A <- row 2i+2 (lead ~1 row-pair)
        // ---- row B ----
        "s_waitcnt vmcnt(17)\n\t"
        EINB
        FIN("228")
        LDB                                    // refill B <- row 2i+3
        "v_add_u32 v94, 0x200, v94\n\t"
        "v_min_u32 v94, 0x1fe00, v94\n\t"      // clamp: last refill re-reads pair 510/511
        "v_add_u32 v95, 8, v95\n\t"
        "v_min_u32 v95, 0x7f8, v95\n\t"
        "s_add_u32 s29, s29, 1\n\t"
        "s_cmp_lg_u32 s29, 256\n\t"
        "s_cbranch_scc1 Lrvq_%=\n\t"
        "s_waitcnt vmcnt(0)\n\t"               // drain trailing refills before regs go dead
        "v_mov_b32 %[ob], v89\n\t"
        "v_mov_b32 %[oi], v90\n\t"
        : [ob] "=v"(best), [oi] "=v"(bidx)
        : [ra] "v"(ra), [cb] "s"(cbw), [c2] "s"(c2w), [m0] "s"(m0)
        : "vcc", "scc", "s29",
          "v16","v17","v18","v19","v20","v21","v22","v23","v24","v25","v26","v27",
          "v28","v29","v30","v31","v32","v33","v34","v35","v36","v37","v38","v39",
          "v40","v41","v42","v43","v44","v45","v46","v47","v48","v49","v50","v51",
          "v52","v53","v54","v55","v56","v57","v58","v59","v60","v61","v62","v63",
          "v64","v65","v66","v67","v68","v69","v70","v71","v72","v73","v74","v75",
          "v76","v77","v78","v79","v80","v81","v82","v83","v84","v85","v86","v87",
          "v88","v89","v90","v91","v92","v93","v94","v95","v96","v97","v98","v99",
          "v100","v101","v102","v103","v104","v105","v106","v107","v108","v109",
          "v110","v111","v112","v113","v114","v115","v116","v117","v118","v119",
          "v120","v121","v122","v123","v124","v125","v126","v127","v128","v129",
          "v130","v131","v132","v133","v134","v135","v136","v137","v138","v139",
          "v140","v141","v142","v143","v144","v145","v146","v147","v148","v149",
          "v150","v151","v152","v153","v154","v155","v156","v157","v158","v159",
          "v160","v161","v162","v163","v164","v165","v166","v167","v168","v169",
          "v170","v171","v172","v173","v174","v175","v176","v177","v178","v179",
          "v180","v181","v182","v183","v184","v185","v186","v187","v188","v189",
          "v190","v191","v192","v193","v194","v195","v196","v197","v198","v199",
          "v200","v201","v202","v203","v204","v205","v206","v207","v208","v209",
          "v210","v211","v212","v213","v214","v215","v216","v217","v218","v219",
          "v220","v221","v222","v223","v224","v225","v226","v227","v228");

    // --- combine across the 4 m-chunks (waves), first-occurrence semantics ---
    __shared__ float sb[WPB * 64];
    __shared__ int   si[WPB * 64];
    __shared__ int   fidx[64];
    sb[wv * 64 + lane] = best;
    si[wv * 64 + lane] = bidx;
    __syncthreads();
    if (tid < 64) {
        float b = sb[lane];
        int ix = si[lane];
#pragma unroll
        for (int w = 1; w < WPB; ++w) {
            float ob = sb[w * 64 + lane];
            int oi = si[w * 64 + lane];
            if (ob < b) { b = ob; ix = oi; }  // strict <: smaller-m chunk wins ties
        }
        fidx[lane] = ix;
        idx_out[point] = (float)ix;  // exact for ix < 2^24
    }
    __syncthreads();

    // --- residual update: 256 threads x 16 elems, coalesced on res ---
    const size_t base = (size_t)blockIdx.x * 64 * DD;
#pragma unroll
    for (int i = 0; i < 16; ++i) {
        const int e = i * 256 + tid;
        const int p = e >> 6;
        const int d = e & 63;
        const int ix = fidx[p];
        res_out[base + e] = res_in[base + e] - cbk[(size_t)ix * DD + d];  // exact fp32 sub
    }
}

// ---- finalize: quantized = x - residual ----
__global__ __launch_bounds__(256) void rvq_final(const float* __restrict__ x,
                                                 const float* __restrict__ res,
                                                 float* __restrict__ q) {
#pragma clang fp contract(off)
    int i = blockIdx.x * 256 + threadIdx.x;
    q[i] = x[i] - res[i];
}

extern "C" void kernel_launch(void* const* d_in, const int* in_sizes, int n_in,
                              void* d_out, int out_size, void* d_ws, size_t ws_size,
                              hipStream_t stream) {
    const float* x  = (const float*)d_in[0];
    const float* cb = (const float*)d_in[1];

    float* out = (float*)d_out;
    float* quant = out;                 // QSIZE floats
    float* idx_out = out + QSIZE;       // K*NPTS floats (indices as float)

    float* c2   = (float*)d_ws;                       // K*M floats (64 KB)
    float* res1 = c2 + (size_t)KK * MM;               // NPTS*D floats (8 MB), 16B-aligned
    float* R[2] = { quant, res1 };                    // ping-pong residual (R0 in d_out)

    rvq_prep<<<(KK * MM) / 256, 256, 0, stream>>>(cb, c2);

    for (int k = 0; k < KK; ++k) {
        const float* rin = (k == 0) ? x : R[(k - 1) & 1];
        float* rout = R[k & 1];
        rvq_step<<<NPTS / 64, 256, 0, stream>>>(
            rin, rout,
            cb + (size_t)k * MM * DD,
            c2 + (size_t)k * MM,
            idx_out + (size_t)k * NPTS);
    }

    rvq_final<<<QSIZE / 256, 256, 0, stream>>>(x, R[(KK - 1) & 1], quant);
}

// Round 2
// 1410.200 us; speedup vs baseline: 2.6537x; 2.6537x over previous
//
#include <hip/hip_runtime.h>

// Residual VQ, bit-exact replication of the numpy reference's fp32 rounding.
// B=16 S=2048 D=64 K=8 M=2048.
//
// Numerics contract (verified bit-exact R1-R5, absmax 0.0):
//  - r2/c2: numpy pairwise_sum 8-accumulator order, no FMA contraction
//  - cross: numpy einsum baseline-SSE order: 4 chains (d mod 4), per 16-block
//           groups at offsets {12,8,4,0}+j, blocks ascending, hsum (L0+L1)+(L2+L3)
//  - t = fl(r2 - 2*cross) via fma(-2,cross,r2); d2 = fl(t + c2)
//  - argmin: first occurrence (strict <; cross-chunk combine ascending-m)
//
// R7: R6's VMEM-broadcast ping-pong FAILED (498 us/step): wave-uniform
// global_load still pays per-lane TA address processing (~16cy/instr on the
// single per-CU vector-memory pipe) -> pipe-bound at 26% VALU. Wave-uniform
// data must ride the scalar path. Reverted to the proven R5 SMEM loop
// (byte-identical hot loop below).
// R5's 28% stall: 16 waves/CU each streaming a PRIVATE 64KB codebook chunk
// -> K$ never hits, 5 scalar misses/row/wave queue up (~700cy effective).
// SGPR double-buffer impossible (2 rows = 128 > 102 SGPR ceiling). Instead:
// wave-PAIR chunk sharing. Block = 1024 threads = 16 waves = 8 chunks x 2
// point-halves over 128 points; grid = 256 = 1 block/CU. Waves 2c,2c+1 walk
// the same rows -> K$ miss-combining halves scalar miss traffic and the
// follower hits. Zero hot-loop changes; downside bounded (drift => R5 perf).

#define BB 16
#define SS 2048
#define DD 64
#define KK 8
#define MM 2048
#define NPTS (BB * SS)      // 32768
#define QSIZE (NPTS * DD)   // 2097152
#define WPB 16              // waves per block: 8 m-chunks x 2 point-halves
#define NCHUNK 8
#define PPB 128             // points per block
#define MCHUNK (MM / NCHUNK)  // 256 m per wave

// ---- prep: c2[k][m] (numpy pairwise) ----
__global__ __launch_bounds__(256) void rvq_prep(const float* __restrict__ cb,
                                                float* __restrict__ c2) {
#pragma clang fp contract(off)
    int tid = blockIdx.x * 256 + threadIdx.x;  // 0 .. K*M-1
    const float* row = cb + (size_t)tid * DD;
    float r[8];
#pragma unroll
    for (int j = 0; j < 8; ++j) { float v = row[j]; r[j] = v * v; }
#pragma unroll
    for (int i = 8; i < DD; i += 8) {
#pragma unroll
        for (int j = 0; j < 8; ++j) { float v = row[i + j]; float t = v * v; r[j] += t; }
    }
    c2[tid] = ((r[0] + r[1]) + (r[2] + r[3])) + ((r[4] + r[5]) + (r[6] + r[7]));
}

// r2 chain block for k-th 8-float group (bases A=16+8k, etc.)
#define R2K(A, B, C, E) \
    "v_pk_mul_f32 v[92:93], v[" A "], v[" A "]\n\t" \
    "v_pk_add_f32 v[80:81], v[80:81], v[92:93]\n\t" \
    "v_pk_mul_f32 v[92:93], v[" B "], v[" B "]\n\t" \
    "v_pk_add_f32 v[82:83], v[82:83], v[92:93]\n\t" \
    "v_pk_mul_f32 v[92:93], v[" C "], v[" C "]\n\t" \
    "v_pk_add_f32 v[84:85], v[84:85], v[92:93]\n\t" \
    "v_pk_mul_f32 v[92:93], v[" E "], v[" E "]\n\t" \
    "v_pk_add_f32 v[86:87], v[86:87], v[92:93]\n\t"

// einsum group at offset d0: s-pairs (32+d0, 34+d0), v-pairs (16+d0, 18+d0)
#define GRP(SA, SB, VA, VB) \
    "v_pk_mul_f32 v[84:85], s[" SA "], v[" VA "]\n\t" \
    "v_pk_mul_f32 v[86:87], s[" SB "], v[" VB "]\n\t" \
    "v_pk_add_f32 v[80:81], v[80:81], v[84:85]\n\t" \
    "v_pk_add_f32 v[82:83], v[82:83], v[86:87]\n\t"

// ---- one RVQ step ----
// grid = NPTS/PPB = 256 blocks x 1024 threads (16 waves).
// wave wv: chunk c = wv>>1, point-half h = wv&1. Waves 2c,2c+1 share chunk c's
// scalar stream (K$ dedup). lane = point within the half.
__global__ __launch_bounds__(1024, 4) void rvq_step(const float* __restrict__ res_in,
                                                    float* __restrict__ res_out,
                                                    const float* __restrict__ cbk,  // (M,D)
                                                    const float* __restrict__ c2k,  // (M,)
                                                    float* __restrict__ idx_out) {  // (NPTS,)
#pragma clang fp contract(off)
    const int tid = threadIdx.x;
    const int lane = tid & 63;
    const int wv = __builtin_amdgcn_readfirstlane(tid >> 6);  // wave-uniform, 0..15
    const int ch = wv >> 1;                                   // m-chunk 0..7
    const int hf = wv & 1;                                    // point-half 0..1
    const int point = blockIdx.x * PPB + hf * 64 + lane;

    const int m0 = ch * MCHUNK;
    const float* cbw = cbk + (size_t)m0 * DD;   // this wave's chunk base
    const float* c2w = c2k + m0;
    const unsigned long long ra = (unsigned long long)(res_in + (size_t)point * DD);

    float best;
    int bidx;
    asm volatile(
        // ---- residual: 64 floats -> v[16:79] ----
        "global_load_dwordx4 v[16:19], %[ra], off\n\t"
        "global_load_dwordx4 v[20:23], %[ra], off offset:16\n\t"
        "global_load_dwordx4 v[24:27], %[ra], off offset:32\n\t"
        "global_load_dwordx4 v[28:31], %[ra], off offset:48\n\t"
        "global_load_dwordx4 v[32:35], %[ra], off offset:64\n\t"
        "global_load_dwordx4 v[36:39], %[ra], off offset:80\n\t"
        "global_load_dwordx4 v[40:43], %[ra], off offset:96\n\t"
        "global_load_dwordx4 v[44:47], %[ra], off offset:112\n\t"
        "global_load_dwordx4 v[48:51], %[ra], off offset:128\n\t"
        "global_load_dwordx4 v[52:55], %[ra], off offset:144\n\t"
        "global_load_dwordx4 v[56:59], %[ra], off offset:160\n\t"
        "global_load_dwordx4 v[60:63], %[ra], off offset:176\n\t"
        "global_load_dwordx4 v[64:67], %[ra], off offset:192\n\t"
        "global_load_dwordx4 v[68:71], %[ra], off offset:208\n\t"
        "global_load_dwordx4 v[72:75], %[ra], off offset:224\n\t"
        "global_load_dwordx4 v[76:79], %[ra], off offset:240\n\t"
        "s_waitcnt vmcnt(0)\n\t"
        // ---- r2, numpy pairwise 8-acc order; accs (r0,r1)..(r6,r7) in v[80:87] ----
        "v_pk_mul_f32 v[80:81], v[16:17], v[16:17]\n\t"
        "v_pk_mul_f32 v[82:83], v[18:19], v[18:19]\n\t"
        "v_pk_mul_f32 v[84:85], v[20:21], v[20:21]\n\t"
        "v_pk_mul_f32 v[86:87], v[22:23], v[22:23]\n\t"
        R2K("24:25", "26:27", "28:29", "30:31")
        R2K("32:33", "34:35", "36:37", "38:39")
        R2K("40:41", "42:43", "44:45", "46:47")
        R2K("48:49", "50:51", "52:53", "54:55")
        R2K("56:57", "58:59", "60:61", "62:63")
        R2K("64:65", "66:67", "68:69", "70:71")
        R2K("72:73", "74:75", "76:77", "78:79")
        "v_add_f32 v92, v80, v81\n\t"
        "v_add_f32 v93, v82, v83\n\t"
        "v_add_f32 v92, v92, v93\n\t"
        "v_add_f32 v93, v84, v85\n\t"
        "v_add_f32 v88, v86, v87\n\t"
        "v_add_f32 v93, v93, v88\n\t"
        "v_add_f32 v88, v92, v93\n\t"          // r2 -> v88
        // ---- init ----
        "v_mov_b32 v89, 0x7f800000\n\t"        // best = +inf
        "v_mov_b32 v90, 0\n\t"                 // bidx = 0
        "s_mov_b32 s29, 0\n\t"                 // byte offset in chunk
        "Lrvq_%=:\n\t"
        // ---- codebook row m -> s[32:95]; c2m -> s28; m -> v91 ----
        "s_load_dwordx16 s[32:47], %[cb], s29\n\t"
        "s_add_u32 s30, s29, 64\n\t"
        "s_load_dwordx16 s[48:63], %[cb], s30\n\t"
        "s_add_u32 s30, s29, 128\n\t"
        "s_load_dwordx16 s[64:79], %[cb], s30\n\t"
        "s_add_u32 s30, s29, 192\n\t"
        "s_load_dwordx16 s[80:95], %[cb], s30\n\t"
        "s_lshr_b32 s31, s29, 6\n\t"
        "s_load_dword s28, %[c2], s31\n\t"
        "s_lshr_b32 s30, s29, 8\n\t"
        "s_add_u32 s30, s30, %[m0]\n\t"
        "v_mov_b32 v91, s30\n\t"
        "s_waitcnt lgkmcnt(0)\n\t"
        // ---- einsum: blocks ascending, groups {12,8,4,0}+b; chains in v[80:83] ----
        // b=0: d0=12 (init), 8, 4, 0
        "v_pk_mul_f32 v[80:81], s[44:45], v[28:29]\n\t"
        "v_pk_mul_f32 v[82:83], s[46:47], v[30:31]\n\t"
        GRP("40:41", "42:43", "24:25", "26:27")
        GRP("36:37", "38:39", "20:21", "22:23")
        GRP("32:33", "34:35", "16:17", "18:19")
        // b=16: d0=28, 24, 20, 16
        GRP("60:61", "62:63", "44:45", "46:47")
        GRP("56:57", "58:59", "40:41", "42:43")
        GRP("52:53", "54:55", "36:37", "38:39")
        GRP("48:49", "50:51", "32:33", "34:35")
        // b=32: d0=44, 40, 36, 32
        GRP("76:77", "78:79", "60:61", "62:63")
        GRP("72:73", "74:75", "56:57", "58:59")
        GRP("68:69", "70:71", "52:53", "54:55")
        GRP("64:65", "66:67", "48:49", "50:51")
        // b=48: d0=60, 56, 52, 48
        GRP("92:93", "94:95", "76:77", "78:79")
        GRP("88:89", "90:91", "72:73", "74:75")
        GRP("84:85", "86:87", "68:69", "70:71")
        GRP("80:81", "82:83", "64:65", "66:67")
        // ---- hsum, d2, argmin ----
        "v_add_f32 v92, v80, v81\n\t"
        "v_add_f32 v93, v82, v83\n\t"
        "v_add_f32 v92, v92, v93\n\t"          // cross
        "v_fma_f32 v92, v92, -2.0, v88\n\t"    // tt = -2*cross + r2 (single rounding)
        "v_add_f32 v92, s28, v92\n\t"          // d2 = tt + c2m (commutative, exact)
        "v_cmp_lt_f32 vcc, v92, v89\n\t"
        "v_cndmask_b32 v89, v89, v92, vcc\n\t"
        "v_cndmask_b32 v90, v90, v91, vcc\n\t"
        "s_add_u32 s29, s29, 256\n\t"
        "s_cmp_lg_u32 s29, 0x10000\n\t"
        "s_cbranch_scc1 Lrvq_%=\n\t"
        "v_mov_b32 %[ob], v89\n\t"
        "v_mov_b32 %[oi], v90\n\t"
        : [ob] "=v"(best), [oi] "=v"(bidx)
        : [ra] "v"(ra), [cb] "s"(cbw), [c2] "s"(c2w), [m0] "s"(m0)
        : "vcc", "scc",
          "v16","v17","v18","v19","v20","v21","v22","v23","v24","v25","v26","v27",
          "v28","v29","v30","v31","v32","v33","v34","v35","v36","v37","v38","v39",
          "v40","v41","v42","v43","v44","v45","v46","v47","v48","v49","v50","v51",
          "v52","v53","v54","v55","v56","v57","v58","v59","v60","v61","v62","v63",
          "v64","v65","v66","v67","v68","v69","v70","v71","v72","v73","v74","v75",
          "v76","v77","v78","v79","v80","v81","v82","v83","v84","v85","v86","v87",
          "v88","v89","v90","v91","v92","v93",
          "s28","s29","s30","s31","s32","s33","s34","s35","s36","s37","s38","s39",
          "s40","s41","s42","s43","s44","s45","s46","s47","s48","s49","s50","s51",
          "s52","s53","s54","s55","s56","s57","s58","s59","s60","s61","s62","s63",
          "s64","s65","s66","s67","s68","s69","s70","s71","s72","s73","s74","s75",
          "s76","s77","s78","s79","s80","s81","s82","s83","s84","s85","s86","s87",
          "s88","s89","s90","s91","s92","s93","s94","s95");

    // --- combine across the 8 m-chunks (wave pairs), first-occurrence ---
    __shared__ float sb[WPB * 64];
    __shared__ int   si[WPB * 64];
    __shared__ int   fidx[PPB];
    sb[wv * 64 + lane] = best;
    si[wv * 64 + lane] = bidx;
    __syncthreads();
    if (tid < PPB) {
        // point p = blockIdx*PPB + tid; tid = h*64 + l
        const int h = tid >> 6;
        const int l = tid & 63;
        float b = sb[h * 64 + l];          // chunk 0 = wave h
        int ix = si[h * 64 + l];
#pragma unroll
        for (int c = 1; c < NCHUNK; ++c) {  // ascending chunk = ascending m
            const int w = c * 2 + h;
            float ob = sb[w * 64 + l];
            int oi = si[w * 64 + l];
            if (ob < b) { b = ob; ix = oi; }  // strict <: smaller-m chunk wins ties
        }
        fidx[tid] = ix;
        idx_out[blockIdx.x * PPB + tid] = (float)ix;  // exact for ix < 2^24
    }
    __syncthreads();

    // --- residual update: 1024 threads x 8 elems, coalesced on res ---
    const size_t base = (size_t)blockIdx.x * PPB * DD;
#pragma unroll
    for (int i = 0; i < 8; ++i) {
        const int e = i * 1024 + tid;
        const int p = e >> 6;
        const int d = e & 63;
        const int ix = fidx[p];
        res_out[base + e] = res_in[base + e] - cbk[(size_t)ix * DD + d];  // exact fp32 sub
    }
}

// ---- finalize: quantized = x - residual ----
__global__ __launch_bounds__(256) void rvq_final(const float* __restrict__ x,
                                                 const float* __restrict__ res,
                                                 float* __restrict__ q) {
#pragma clang fp contract(off)
    int i = blockIdx.x * 256 + threadIdx.x;
    q[i] = x[i] - res[i];
}

extern "C" void kernel_launch(void* const* d_in, const int* in_sizes, int n_in,
                              void* d_out, int out_size, void* d_ws, size_t ws_size,
                              hipStream_t stream) {
    const float* x  = (const float*)d_in[0];
    const float* cb = (const float*)d_in[1];

    float* out = (float*)d_out;
    float* quant = out;                 // QSIZE floats
    float* idx_out = out + QSIZE;       // K*NPTS floats (indices as float)

    float* c2   = (float*)d_ws;                       // K*M floats (64 KB)
    float* res1 = c2 + (size_t)KK * MM;               // NPTS*D floats (8 MB), 16B-aligned
    float* R[2] = { quant, res1 };                    // ping-pong residual (R0 in d_out)

    rvq_prep<<<(KK * MM) / 256, 256, 0, stream>>>(cb, c2);

    for (int k = 0; k < KK; ++k) {
        const float* rin = (k == 0) ? x : R[(k - 1) & 1];
        float* rout = R[k & 1];
        rvq_step<<<NPTS / PPB, 1024, 0, stream>>>(
            rin, rout,
            cb + (size_t)k * MM * DD,
            c2 + (size_t)k * MM,
            idx_out + (size_t)k * NPTS);
    }

    rvq_final<<<QSIZE / 256, 256, 0, stream>>>(x, R[(KK - 1) & 1], quant);
}

// Round 3
// 1349.767 us; speedup vs baseline: 2.7725x; 1.0448x over previous
//
#include <hip/hip_runtime.h>

// Residual VQ, bit-exact replication of the numpy reference's fp32 rounding.
// B=16 S=2048 D=64 K=8 M=2048.
//
// Numerics contract (verified bit-exact R1-R5, absmax 0.0):
//  - r2/c2: numpy pairwise_sum 8-accumulator order, no FMA contraction
//  - cross: numpy einsum baseline-SSE order: 4 chains (d mod 4), per 16-block
//           groups at offsets {12,8,4,0}+j, blocks ascending, hsum (L0+L1)+(L2+L3)
//  - t = fl(r2 - 2*cross) via fma(-2,cross,r2); d2 = fl(t + c2)
//  - argmin: first occurrence == u64-min over key {d2_bits(hi), m(lo)} (d2>0)
//
// R8: R7's pair-sharing was null because pairs sat on different SIMDs with no
// resync (drift > sL1 stream history ~6 rows -> zero reuse). This round:
// 8-way sharing with enforced lockstep. Block = 8 waves, ALL on the SAME
// 256-row chunk, 8 point-groups (512 points). Grid = 64 groups x 8 chunks
// = 512 blocks = exactly 2 blocks/CU -> only 2 scalar streams per CU
// (~25 rows of sL1 history) and s_barrier every 8 rows bounds skew to <=8
// rows -> each 64B line misses once, hits 7x. Effective SMEM latency drops
// from ~1200cy (5 serial L2 misses) to hideable by the 4 resident waves/SIMD.
// Cross-chunk argmin via one global atomicMin(u64 {d2,m}) per point per wave;
// a fused update kernel unpacks, writes idx, updates the residual (identical
// fl(res-cb) sub), resets keys, and on the last step emits quant = fl(x-r).
// Hot-loop instruction stream is byte-identical to the verified R5 loop plus
// a 4-SALU barrier check.

#define BB 16
#define SS 2048
#define DD 64
#define KK 8
#define MM 2048
#define NPTS (BB * SS)      // 32768
#define QSIZE (NPTS * DD)   // 2097152
#define NCHUNK 8
#define WPB 8               // waves per block (all same chunk)
#define PPB 512             // points per block
#define MCHUNK (MM / NCHUNK)  // 256 rows per chunk

// ---- prep: c2[k][m] (numpy pairwise) + key init ----
__global__ __launch_bounds__(256) void rvq_prep(const float* __restrict__ cb,
                                                float* __restrict__ c2,
                                                unsigned long long* __restrict__ keys) {
#pragma clang fp contract(off)
    int tid = blockIdx.x * 256 + threadIdx.x;  // 0 .. K*M-1 = 16383
    const float* row = cb + (size_t)tid * DD;
    float r[8];
#pragma unroll
    for (int j = 0; j < 8; ++j) { float v = row[j]; r[j] = v * v; }
#pragma unroll
    for (int i = 8; i < DD; i += 8) {
#pragma unroll
        for (int j = 0; j < 8; ++j) { float v = row[i + j]; float t = v * v; r[j] += t; }
    }
    c2[tid] = ((r[0] + r[1]) + (r[2] + r[3])) + ((r[4] + r[5]) + (r[6] + r[7]));
    keys[tid] = ~0ULL;                 // NPTS = 2 * K*M
    keys[tid + KK * MM] = ~0ULL;
}

// r2 chain block for k-th 8-float group (bases A=16+8k, etc.)
#define R2K(A, B, C, E) \
    "v_pk_mul_f32 v[92:93], v[" A "], v[" A "]\n\t" \
    "v_pk_add_f32 v[80:81], v[80:81], v[92:93]\n\t" \
    "v_pk_mul_f32 v[92:93], v[" B "], v[" B "]\n\t" \
    "v_pk_add_f32 v[82:83], v[82:83], v[92:93]\n\t" \
    "v_pk_mul_f32 v[92:93], v[" C "], v[" C "]\n\t" \
    "v_pk_add_f32 v[84:85], v[84:85], v[92:93]\n\t" \
    "v_pk_mul_f32 v[92:93], v[" E "], v[" E "]\n\t" \
    "v_pk_add_f32 v[86:87], v[86:87], v[92:93]\n\t"

// einsum group at offset d0: s-pairs (32+d0, 34+d0), v-pairs (16+d0, 18+d0)
#define GRP(SA, SB, VA, VB) \
    "v_pk_mul_f32 v[84:85], s[" SA "], v[" VA "]\n\t" \
    "v_pk_mul_f32 v[86:87], s[" SB "], v[" VB "]\n\t" \
    "v_pk_add_f32 v[80:81], v[80:81], v[84:85]\n\t" \
    "v_pk_add_f32 v[82:83], v[82:83], v[86:87]\n\t"

// ---- main: per-chunk argmin, atomicMin-combined ----
// grid = 512 blocks x 512 threads (8 waves). Block b: chunk = b & 7,
// point-group = b >> 3. All 8 waves of a block walk the SAME codebook rows
// (sL1 8-way reuse), lockstepped by s_barrier every 8 rows.
__global__ __launch_bounds__(512, 4) void rvq_main(const float* __restrict__ res_in,
                                                   const float* __restrict__ cbk,  // (M,D)
                                                   const float* __restrict__ c2k,  // (M,)
                                                   unsigned long long* __restrict__ keys) {
#pragma clang fp contract(off)
    const int tid = threadIdx.x;
    const int lane = tid & 63;
    const int wv = __builtin_amdgcn_readfirstlane(tid >> 6);  // 0..7
    const int ch = blockIdx.x & (NCHUNK - 1);
    const int bp = blockIdx.x >> 3;
    const int point = bp * PPB + wv * 64 + lane;

    const int m0 = ch * MCHUNK;
    const float* cbw = cbk + (size_t)m0 * DD;   // this block's chunk base
    const float* c2w = c2k + m0;
    const unsigned long long ra = (unsigned long long)(res_in + (size_t)point * DD);

    float best;
    int bidx;
    asm volatile(
        // ---- residual: 64 floats -> v[16:79] ----
        "global_load_dwordx4 v[16:19], %[ra], off\n\t"
        "global_load_dwordx4 v[20:23], %[ra], off offset:16\n\t"
        "global_load_dwordx4 v[24:27], %[ra], off offset:32\n\t"
        "global_load_dwordx4 v[28:31], %[ra], off offset:48\n\t"
        "global_load_dwordx4 v[32:35], %[ra], off offset:64\n\t"
        "global_load_dwordx4 v[36:39], %[ra], off offset:80\n\t"
        "global_load_dwordx4 v[40:43], %[ra], off offset:96\n\t"
        "global_load_dwordx4 v[44:47], %[ra], off offset:112\n\t"
        "global_load_dwordx4 v[48:51], %[ra], off offset:128\n\t"
        "global_load_dwordx4 v[52:55], %[ra], off offset:144\n\t"
        "global_load_dwordx4 v[56:59], %[ra], off offset:160\n\t"
        "global_load_dwordx4 v[60:63], %[ra], off offset:176\n\t"
        "global_load_dwordx4 v[64:67], %[ra], off offset:192\n\t"
        "global_load_dwordx4 v[68:71], %[ra], off offset:208\n\t"
        "global_load_dwordx4 v[72:75], %[ra], off offset:224\n\t"
        "global_load_dwordx4 v[76:79], %[ra], off offset:240\n\t"
        "s_waitcnt vmcnt(0)\n\t"
        // ---- r2, numpy pairwise 8-acc order; accs (r0,r1)..(r6,r7) in v[80:87] ----
        "v_pk_mul_f32 v[80:81], v[16:17], v[16:17]\n\t"
        "v_pk_mul_f32 v[82:83], v[18:19], v[18:19]\n\t"
        "v_pk_mul_f32 v[84:85], v[20:21], v[20:21]\n\t"
        "v_pk_mul_f32 v[86:87], v[22:23], v[22:23]\n\t"
        R2K("24:25", "26:27", "28:29", "30:31")
        R2K("32:33", "34:35", "36:37", "38:39")
        R2K("40:41", "42:43", "44:45", "46:47")
        R2K("48:49", "50:51", "52:53", "54:55")
        R2K("56:57", "58:59", "60:61", "62:63")
        R2K("64:65", "66:67", "68:69", "70:71")
        R2K("72:73", "74:75", "76:77", "78:79")
        "v_add_f32 v92, v80, v81\n\t"
        "v_add_f32 v93, v82, v83\n\t"
        "v_add_f32 v92, v92, v93\n\t"
        "v_add_f32 v93, v84, v85\n\t"
        "v_add_f32 v88, v86, v87\n\t"
        "v_add_f32 v93, v93, v88\n\t"
        "v_add_f32 v88, v92, v93\n\t"          // r2 -> v88
        // ---- init ----
        "v_mov_b32 v89, 0x7f800000\n\t"        // best = +inf
        "v_mov_b32 v90, 0\n\t"                 // bidx = 0
        "s_mov_b32 s29, 0\n\t"                 // byte offset in chunk
        "Lrvq_%=:\n\t"
        // ---- lockstep: barrier every 8 rows (2048 B) keeps the 8 waves'
        //      shared scalar stream within sL1 history ----
        "s_and_b32 s30, s29, 0x7ff\n\t"
        "s_cmp_lg_u32 s30, 0\n\t"
        "s_cbranch_scc1 Lnb_%=\n\t"
        "s_barrier\n\t"
        "Lnb_%=:\n\t"
        // ---- codebook row m -> s[32:95]; c2m -> s28; m -> v91 ----
        "s_load_dwordx16 s[32:47], %[cb], s29\n\t"
        "s_add_u32 s30, s29, 64\n\t"
        "s_load_dwordx16 s[48:63], %[cb], s30\n\t"
        "s_add_u32 s30, s29, 128\n\t"
        "s_load_dwordx16 s[64:79], %[cb], s30\n\t"
        "s_add_u32 s30, s29, 192\n\t"
        "s_load_dwordx16 s[80:95], %[cb], s30\n\t"
        "s_lshr_b32 s31, s29, 6\n\t"
        "s_load_dword s28, %[c2], s31\n\t"
        "s_lshr_b32 s30, s29, 8\n\t"
        "s_add_u32 s30, s30, %[m0]\n\t"
        "v_mov_b32 v91, s30\n\t"
        "s_waitcnt lgkmcnt(0)\n\t"
        // ---- einsum: blocks ascending, groups {12,8,4,0}+b; chains in v[80:83] ----
        // b=0: d0=12 (init), 8, 4, 0
        "v_pk_mul_f32 v[80:81], s[44:45], v[28:29]\n\t"
        "v_pk_mul_f32 v[82:83], s[46:47], v[30:31]\n\t"
        GRP("40:41", "42:43", "24:25", "26:27")
        GRP("36:37", "38:39", "20:21", "22:23")
        GRP("32:33", "34:35", "16:17", "18:19")
        // b=16: d0=28, 24, 20, 16
        GRP("60:61", "62:63", "44:45", "46:47")
        GRP("56:57", "58:59", "40:41", "42:43")
        GRP("52:53", "54:55", "36:37", "38:39")
        GRP("48:49", "50:51", "32:33", "34:35")
        // b=32: d0=44, 40, 36, 32
        GRP("76:77", "78:79", "60:61", "62:63")
        GRP("72:73", "74:75", "56:57", "58:59")
        GRP("68:69", "70:71", "52:53", "54:55")
        GRP("64:65", "66:67", "48:49", "50:51")
        // b=48: d0=60, 56, 52, 48
        GRP("92:93", "94:95", "76:77", "78:79")
        GRP("88:89", "90:91", "72:73", "74:75")
        GRP("84:85", "86:87", "68:69", "70:71")
        GRP("80:81", "82:83", "64:65", "66:67")
        // ---- hsum, d2, argmin ----
        "v_add_f32 v92, v80, v81\n\t"
        "v_add_f32 v93, v82, v83\n\t"
        "v_add_f32 v92, v92, v93\n\t"          // cross
        "v_fma_f32 v92, v92, -2.0, v88\n\t"    // tt = -2*cross + r2 (single rounding)
        "v_add_f32 v92, s28, v92\n\t"          // d2 = tt + c2m (commutative, exact)
        "v_cmp_lt_f32 vcc, v92, v89\n\t"
        "v_cndmask_b32 v89, v89, v92, vcc\n\t"
        "v_cndmask_b32 v90, v90, v91, vcc\n\t"
        "s_add_u32 s29, s29, 256\n\t"
        "s_cmp_lg_u32 s29, 0x10000\n\t"
        "s_cbranch_scc1 Lrvq_%=\n\t"
        "v_mov_b32 %[ob], v89\n\t"
        "v_mov_b32 %[oi], v90\n\t"
        : [ob] "=v"(best), [oi] "=v"(bidx)
        : [ra] "v"(ra), [cb] "s"(cbw), [c2] "s"(c2w), [m0] "s"(m0)
        : "vcc", "scc",
          "v16","v17","v18","v19","v20","v21","v22","v23","v24","v25","v26","v27",
          "v28","v29","v30","v31","v32","v33","v34","v35","v36","v37","v38","v39",
          "v40","v41","v42","v43","v44","v45","v46","v47","v48","v49","v50","v51",
          "v52","v53","v54","v55","v56","v57","v58","v59","v60","v61","v62","v63",
          "v64","v65","v66","v67","v68","v69","v70","v71","v72","v73","v74","v75",
          "v76","v77","v78","v79","v80","v81","v82","v83","v84","v85","v86","v87",
          "v88","v89","v90","v91","v92","v93",
          "s28","s29","s30","s31","s32","s33","s34","s35","s36","s37","s38","s39",
          "s40","s41","s42","s43","s44","s45","s46","s47","s48","s49","s50","s51",
          "s52","s53","s54","s55","s56","s57","s58","s59","s60","s61","s62","s63",
          "s64","s65","s66","s67","s68","s69","s70","s71","s72","s73","s74","s75",
          "s76","s77","s78","s79","s80","s81","s82","s83","s84","s85","s86","s87",
          "s88","s89","s90","s91","s92","s93","s94","s95");

    // ---- cross-chunk combine: u64-min over {d2_bits, m}. d2 > 0 always, so
    // u64 order == (d2, then m) == reference first-occurrence semantics.
    unsigned long long key =
        ((unsigned long long)__float_as_uint(best) << 32) | (unsigned int)bidx;
    atomicMin(&keys[point], key);
}

// ---- update: unpack winner, write idx, residual update, key reset ----
// grid = QSIZE/256. Block covers 4 points x 64 dims.
__global__ __launch_bounds__(256) void rvq_update(const float* __restrict__ res_in,
                                                  float* __restrict__ res_out,
                                                  const float* __restrict__ x,
                                                  const float* __restrict__ cbk,  // (M,D)
                                                  unsigned long long* __restrict__ keys,
                                                  float* __restrict__ idx_out,
                                                  int last) {
#pragma clang fp contract(off)
    __shared__ unsigned long long sk[4];
    const int tid = threadIdx.x;
    const int e = blockIdx.x * 256 + tid;
    const int p0 = blockIdx.x * 4;
    if (tid < 4) {
        unsigned long long k = keys[p0 + tid];
        sk[tid] = k;
        keys[p0 + tid] = ~0ULL;                       // reset for next step
        idx_out[p0 + tid] = (float)(unsigned int)k;   // exact for m < 2^24
    }
    __syncthreads();
    const int pi = tid >> 6;
    const int d = tid & 63;
    const int m = (int)(unsigned int)sk[pi];
    const float r = res_in[e] - cbk[(size_t)m * DD + d];  // exact fp32 sub
    if (last) res_out[e] = x[e] - r;   // quant = fl(x - fl(res - cb)); alias-safe
    else      res_out[e] = r;
}

extern "C" void kernel_launch(void* const* d_in, const int* in_sizes, int n_in,
                              void* d_out, int out_size, void* d_ws, size_t ws_size,
                              hipStream_t stream) {
    const float* x  = (const float*)d_in[0];
    const float* cb = (const float*)d_in[1];

    float* out = (float*)d_out;
    float* quant = out;                 // QSIZE floats
    float* idx_out = out + QSIZE;       // K*NPTS floats (indices as float)

    float* c2   = (float*)d_ws;                       // K*M floats (64 KB)
    float* res1 = c2 + (size_t)KK * MM;               // NPTS*D floats (8 MB)
    unsigned long long* keys =
        (unsigned long long*)(res1 + (size_t)QSIZE);  // NPTS u64 (256 KB)
    float* R[2] = { quant, res1 };                    // ping-pong residual

    rvq_prep<<<(KK * MM) / 256, 256, 0, stream>>>(cb, c2, keys);

    for (int k = 0; k < KK; ++k) {
        const float* rin = (k == 0) ? x : R[(k - 1) & 1];
        const int last = (k == KK - 1);
        float* rout = last ? quant : R[k & 1];
        rvq_main<<<(NPTS / PPB) * NCHUNK, PPB, 0, stream>>>(
            rin,
            cb + (size_t)k * MM * DD,
            c2 + (size_t)k * MM,
            keys);
        rvq_update<<<QSIZE / 256, 256, 0, stream>>>(
            rin, rout, x,
            cb + (size_t)k * MM * DD,
            keys,
            idx_out + (size_t)k * NPTS,
            last);
    }
}

// Round 4
// 1317.388 us; speedup vs baseline: 2.8406x; 1.0246x over previous
//
#include <hip/hip_runtime.h>

// Residual VQ, bit-exact replication of the numpy reference's fp32 rounding.
// B=16 S=2048 D=64 K=8 M=2048.
//
// Numerics contract (verified bit-exact, absmax 0.0):
//  - r2/c2: numpy pairwise_sum 8-accumulator order, no FMA contraction
//  - cross: numpy einsum baseline-SSE order: 4 chains (d mod 4), per 16-block
//           groups at offsets {12,8,4,0}+j, blocks ascending, hsum (L0+L1)+(L2+L3)
//  - t = fl(r2 - 2*cross) via fma(-2,cross,r2); d2 = fl(t + c2)
//  - argmin: first occurrence == u64-min over key {d2_bits(hi), m(lo)} (d2>0)
//
// R9: R5/R7/R8 all stuck at ~73% VALU regardless of K$ sharing/lockstep ->
// scalar-path READ-OUT throughput is the cap (~2.4B/cy/CU delivered), cache
// hits don't reduce it; R6 showed the vector path pays per-lane TA cost.
// Fix: split the row across two pipes. d0..31 via SMEM (132B/row), now
// double-buffered (P=s[32:63]/s26, Q=s[64:95]/s27) with a full-einsum issue
// lead and lgkmcnt(0)-only waits; d32..63 via LDS: chunk half-rows staged
// once per block (32KB), then 8x broadcast ds_read_b128/row -> v[96:127].
// Einsum instruction sequence is operand-identical (b32/b48 groups read
// VGPRs instead of SGPRs; same IEEE ops -> bit-exact). ~100cy ds tail per
// row is absorbed by 4-wave TLP (stall budget 3x268cy). R8's atomicMin +
// update-kernel combine kept; lockstep barrier dropped (measured null).

#define BB 16
#define SS 2048
#define DD 64
#define KK 8
#define MM 2048
#define NPTS (BB * SS)      // 32768
#define QSIZE (NPTS * DD)   // 2097152
#define NCHUNK 8
#define WPB 8               // waves per block (all same chunk)
#define PPB 512             // points per block
#define MCHUNK (MM / NCHUNK)  // 256 rows per chunk

// ---- prep: c2[k][m] (numpy pairwise) + key init ----
__global__ __launch_bounds__(256) void rvq_prep(const float* __restrict__ cb,
                                                float* __restrict__ c2,
                                                unsigned long long* __restrict__ keys) {
#pragma clang fp contract(off)
    int tid = blockIdx.x * 256 + threadIdx.x;  // 0 .. K*M-1 = 16383
    const float* row = cb + (size_t)tid * DD;
    float r[8];
#pragma unroll
    for (int j = 0; j < 8; ++j) { float v = row[j]; r[j] = v * v; }
#pragma unroll
    for (int i = 8; i < DD; i += 8) {
#pragma unroll
        for (int j = 0; j < 8; ++j) { float v = row[i + j]; float t = v * v; r[j] += t; }
    }
    c2[tid] = ((r[0] + r[1]) + (r[2] + r[3])) + ((r[4] + r[5]) + (r[6] + r[7]));
    keys[tid] = ~0ULL;                 // NPTS = 2 * K*M
    keys[tid + KK * MM] = ~0ULL;
}

// r2 chain block for k-th 8-float group (bases A=16+8k, etc.)
#define R2K(A, B, C, E) \
    "v_pk_mul_f32 v[92:93], v[" A "], v[" A "]\n\t" \
    "v_pk_add_f32 v[80:81], v[80:81], v[92:93]\n\t" \
    "v_pk_mul_f32 v[92:93], v[" B "], v[" B "]\n\t" \
    "v_pk_add_f32 v[82:83], v[82:83], v[92:93]\n\t" \
    "v_pk_mul_f32 v[92:93], v[" C "], v[" C "]\n\t" \
    "v_pk_add_f32 v[84:85], v[84:85], v[92:93]\n\t" \
    "v_pk_mul_f32 v[92:93], v[" E "], v[" E "]\n\t" \
    "v_pk_add_f32 v[86:87], v[86:87], v[92:93]\n\t"

// einsum group, codebook from SGPR pairs
#define GRP(SA, SB, VA, VB) \
    "v_pk_mul_f32 v[84:85], s[" SA "], v[" VA "]\n\t" \
    "v_pk_mul_f32 v[86:87], s[" SB "], v[" VB "]\n\t" \
    "v_pk_add_f32 v[80:81], v[80:81], v[84:85]\n\t" \
    "v_pk_add_f32 v[82:83], v[82:83], v[86:87]\n\t"

// einsum group, codebook from VGPR pairs (LDS-transported half)
#define GRPL(CA, CB, VA, VB) \
    "v_pk_mul_f32 v[84:85], v[" CA "], v[" VA "]\n\t" \
    "v_pk_mul_f32 v[86:87], v[" CB "], v[" VB "]\n\t" \
    "v_pk_add_f32 v[80:81], v[80:81], v[84:85]\n\t" \
    "v_pk_add_f32 v[82:83], v[82:83], v[86:87]\n\t"

// issue SMEM half-row (d0..31, 128B) + c2 into buffer; clamped prefetch ptr s29
#define SMEMLD(BA, BB, C2D) \
    "s_min_u32 s30, s29, 0xff00\n\t" \
    "s_load_dwordx16 s[" BA "], %[cb], s30\n\t" \
    "s_add_u32 s25, s30, 64\n\t" \
    "s_load_dwordx16 s[" BB "], %[cb], s25\n\t" \
    "s_lshr_b32 s25, s30, 6\n\t" \
    "s_load_dword " C2D ", %[c2], s25\n\t" \
    "s_add_u32 s29, s29, 256\n\t"

// issue LDS half-row (d32..63, 128B) broadcast -> v[96:127]; advance+clamp v94
#define DSLD \
    "ds_read_b128 v[96:99],   v94\n\t" \
    "ds_read_b128 v[100:103], v94 offset:16\n\t" \
    "ds_read_b128 v[104:107], v94 offset:32\n\t" \
    "ds_read_b128 v[108:111], v94 offset:48\n\t" \
    "ds_read_b128 v[112:115], v94 offset:64\n\t" \
    "ds_read_b128 v[116:119], v94 offset:80\n\t" \
    "ds_read_b128 v[120:123], v94 offset:96\n\t" \
    "ds_read_b128 v[124:127], v94 offset:112\n\t" \
    "v_add_u32 v94, 0x80, v94\n\t" \
    "v_min_u32 v94, v95, v94\n\t"

// LDS-half einsum tail: b=32 then b=48, groups {12,8,4,0}+b; d -> v[64+d]
#define EINL \
    GRPL("108:109","110:111","60:61","62:63") \
    GRPL("104:105","106:107","56:57","58:59") \
    GRPL("100:101","102:103","52:53","54:55") \
    GRPL("96:97","98:99","48:49","50:51") \
    GRPL("124:125","126:127","76:77","78:79") \
    GRPL("120:121","122:123","72:73","74:75") \
    GRPL("116:117","118:119","68:69","70:71") \
    GRPL("112:113","114:115","64:65","66:67")

// SMEM-half einsum from P buffer s[32:63]: b=0 (init), b=16
#define EINP \
    "v_pk_mul_f32 v[80:81], s[44:45], v[28:29]\n\t" \
    "v_pk_mul_f32 v[82:83], s[46:47], v[30:31]\n\t" \
    GRP("40:41","42:43","24:25","26:27") \
    GRP("36:37","38:39","20:21","22:23") \
    GRP("32:33","34:35","16:17","18:19") \
    GRP("60:61","62:63","44:45","46:47") \
    GRP("56:57","58:59","40:41","42:43") \
    GRP("52:53","54:55","36:37","38:39") \
    GRP("48:49","50:51","32:33","34:35") \
    EINL

// SMEM-half einsum from Q buffer s[64:95]
#define EINQ \
    "v_pk_mul_f32 v[80:81], s[76:77], v[28:29]\n\t" \
    "v_pk_mul_f32 v[82:83], s[78:79], v[30:31]\n\t" \
    GRP("72:73","74:75","24:25","26:27") \
    GRP("68:69","70:71","20:21","22:23") \
    GRP("64:65","66:67","16:17","18:19") \
    GRP("92:93","94:95","44:45","46:47") \
    GRP("88:89","90:91","40:41","42:43") \
    GRP("84:85","86:87","36:37","38:39") \
    GRP("80:81","82:83","32:33","34:35") \
    EINL

// hsum, d2, argmin update; C2S = SGPR holding c2 of this row
#define FINX(C2S) \
    "v_add_f32 v92, v80, v81\n\t" \
    "v_add_f32 v93, v82, v83\n\t" \
    "v_add_f32 v92, v92, v93\n\t" \
    "v_fma_f32 v92, v92, -2.0, v88\n\t" \
    "v_add_f32 v92, " C2S ", v92\n\t" \
    "v_cmp_lt_f32 vcc, v92, v89\n\t" \
    "v_cndmask_b32 v89, v89, v92, vcc\n\t" \
    "v_cndmask_b32 v90, v90, v91, vcc\n\t" \
    "v_add_u32 v91, 1, v91\n\t"

// ---- main: per-chunk argmin, atomicMin-combined ----
// grid = 512 blocks x 512 threads (8 waves). Block b: chunk = b & 7,
// point-group = b >> 3. 2 blocks/CU, 4 waves/SIMD, 32KB LDS/block.
__global__ __launch_bounds__(512, 4) void rvq_main(const float* __restrict__ res_in,
                                                   const float* __restrict__ cbk,  // (M,D)
                                                   const float* __restrict__ c2k,  // (M,)
                                                   unsigned long long* __restrict__ keys) {
#pragma clang fp contract(off)
    const int tid = threadIdx.x;
    const int lane = tid & 63;
    const int wv = __builtin_amdgcn_readfirstlane(tid >> 6);  // 0..7
    const int ch = blockIdx.x & (NCHUNK - 1);
    const int bp = blockIdx.x >> 3;
    const int point = bp * PPB + wv * 64 + lane;

    const int m0 = ch * MCHUNK;
    const float* cbw = cbk + (size_t)m0 * DD;   // this block's chunk base
    const float* c2w = c2k + m0;
    const unsigned long long ra = (unsigned long long)(res_in + (size_t)point * DD);

    // ---- stage the chunk's half-rows (d=32..63) into LDS: [256 rows][32 f] ----
    __shared__ __align__(16) float lds_cb[MCHUNK * 32];   // 32 KB
    for (int i = tid; i < MCHUNK * 8; i += PPB) {         // 2048 float4s
        const int row = i >> 3;
        const int o = (i & 7) << 2;
        *(float4*)&lds_cb[row * 32 + o] = *(const float4*)(cbw + row * DD + 32 + o);
    }
    __syncthreads();
    const unsigned ldsbase = (unsigned)(unsigned long long)(void*)&lds_cb[0];
    const unsigned ldsclamp = ldsbase + (MCHUNK - 1) * 128;

    float best;
    int bidx;
    asm volatile(
        // ---- residual: 64 floats -> v[16:79] ----
        "global_load_dwordx4 v[16:19], %[ra], off\n\t"
        "global_load_dwordx4 v[20:23], %[ra], off offset:16\n\t"
        "global_load_dwordx4 v[24:27], %[ra], off offset:32\n\t"
        "global_load_dwordx4 v[28:31], %[ra], off offset:48\n\t"
        "global_load_dwordx4 v[32:35], %[ra], off offset:64\n\t"
        "global_load_dwordx4 v[36:39], %[ra], off offset:80\n\t"
        "global_load_dwordx4 v[40:43], %[ra], off offset:96\n\t"
        "global_load_dwordx4 v[44:47], %[ra], off offset:112\n\t"
        "global_load_dwordx4 v[48:51], %[ra], off offset:128\n\t"
        "global_load_dwordx4 v[52:55], %[ra], off offset:144\n\t"
        "global_load_dwordx4 v[56:59], %[ra], off offset:160\n\t"
        "global_load_dwordx4 v[60:63], %[ra], off offset:176\n\t"
        "global_load_dwordx4 v[64:67], %[ra], off offset:192\n\t"
        "global_load_dwordx4 v[68:71], %[ra], off offset:208\n\t"
        "global_load_dwordx4 v[72:75], %[ra], off offset:224\n\t"
        "global_load_dwordx4 v[76:79], %[ra], off offset:240\n\t"
        "s_waitcnt vmcnt(0)\n\t"
        // ---- r2, numpy pairwise 8-acc order; accs in v[80:87] ----
        "v_pk_mul_f32 v[80:81], v[16:17], v[16:17]\n\t"
        "v_pk_mul_f32 v[82:83], v[18:19], v[18:19]\n\t"
        "v_pk_mul_f32 v[84:85], v[20:21], v[20:21]\n\t"
        "v_pk_mul_f32 v[86:87], v[22:23], v[22:23]\n\t"
        R2K("24:25", "26:27", "28:29", "30:31")
        R2K("32:33", "34:35", "36:37", "38:39")
        R2K("40:41", "42:43", "44:45", "46:47")
        R2K("48:49", "50:51", "52:53", "54:55")
        R2K("56:57", "58:59", "60:61", "62:63")
        R2K("64:65", "66:67", "68:69", "70:71")
        R2K("72:73", "74:75", "76:77", "78:79")
        "v_add_f32 v92, v80, v81\n\t"
        "v_add_f32 v93, v82, v83\n\t"
        "v_add_f32 v92, v92, v93\n\t"
        "v_add_f32 v93, v84, v85\n\t"
        "v_add_f32 v88, v86, v87\n\t"
        "v_add_f32 v93, v93, v88\n\t"
        "v_add_f32 v88, v92, v93\n\t"          // r2 -> v88
        // ---- init ----
        "v_mov_b32 v89, 0x7f800000\n\t"        // best = +inf
        "v_mov_b32 v90, 0\n\t"                 // bidx = 0
        "v_mov_b32 v91, %[m0]\n\t"             // current m
        "v_mov_b32 v94, %[lb]\n\t"             // LDS read ptr (row 0)
        "v_mov_b32 v95, %[lc]\n\t"             // LDS ptr clamp (last row)
        "s_mov_b32 s29, 0\n\t"                 // SMEM prefetch byte offset
        SMEMLD("32:47", "48:63", "s26")        // P(0); s29 -> 256
        DSLD                                   // ds(0); v94 -> row 1
        "s_mov_b32 s24, 0\n\t"                 // row-pair counter
        "Ltop_%=:\n\t"
        // ---- row r (even, buffer P): in flight on entry: P(r), ds(r) ----
        "s_waitcnt lgkmcnt(0)\n\t"
        SMEMLD("64:79", "80:95", "s27")        // issue Q(r+1), full-einsum lead
        EINP
        DSLD                                   // issue ds(r+1)
        FINX("s26")
        // ---- row r+1 (odd, buffer Q): in flight: Q(r+1), ds(r+1) ----
        "s_waitcnt lgkmcnt(0)\n\t"
        SMEMLD("32:47", "48:63", "s26")        // issue P(r+2)
        EINQ
        DSLD                                   // issue ds(r+2)
        FINX("s27")
        "s_add_u32 s24, s24, 1\n\t"
        "s_cmp_lg_u32 s24, 128\n\t"
        "s_cbranch_scc1 Ltop_%=\n\t"
        "s_waitcnt lgkmcnt(0)\n\t"             // drain trailing P/ds before regs die
        "v_mov_b32 %[ob], v89\n\t"
        "v_mov_b32 %[oi], v90\n\t"
        : [ob] "=v"(best), [oi] "=v"(bidx)
        : [ra] "v"(ra), [cb] "s"(cbw), [c2] "s"(c2w), [m0] "s"(m0),
          [lb] "s"(ldsbase), [lc] "s"(ldsclamp)
        : "vcc", "scc",
          "s24","s25","s26","s27","s29","s30",
          "s32","s33","s34","s35","s36","s37","s38","s39",
          "s40","s41","s42","s43","s44","s45","s46","s47","s48","s49","s50","s51",
          "s52","s53","s54","s55","s56","s57","s58","s59","s60","s61","s62","s63",
          "s64","s65","s66","s67","s68","s69","s70","s71","s72","s73","s74","s75",
          "s76","s77","s78","s79","s80","s81","s82","s83","s84","s85","s86","s87",
          "s88","s89","s90","s91","s92","s93","s94","s95",
          "v16","v17","v18","v19","v20","v21","v22","v23","v24","v25","v26","v27",
          "v28","v29","v30","v31","v32","v33","v34","v35","v36","v37","v38","v39",
          "v40","v41","v42","v43","v44","v45","v46","v47","v48","v49","v50","v51",
          "v52","v53","v54","v55","v56","v57","v58","v59","v60","v61","v62","v63",
          "v64","v65","v66","v67","v68","v69","v70","v71","v72","v73","v74","v75",
          "v76","v77","v78","v79","v80","v81","v82","v83","v84","v85","v86","v87",
          "v88","v89","v90","v91","v92","v93","v94","v95","v96","v97","v98","v99",
          "v100","v101","v102","v103","v104","v105","v106","v107","v108","v109",
          "v110","v111","v112","v113","v114","v115","v116","v117","v118","v119",
          "v120","v121","v122","v123","v124","v125","v126","v127");

    // ---- cross-chunk combine: u64-min over {d2_bits, m}. d2 > 0 always, so
    // u64 order == (d2, then m) == reference first-occurrence semantics.
    unsigned long long key =
        ((unsigned long long)__float_as_uint(best) << 32) | (unsigned int)bidx;
    atomicMin(&keys[point], key);
}

// ---- update: unpack winner, write idx, residual update, key reset ----
// grid = QSIZE/256. Block covers 4 points x 64 dims.
__global__ __launch_bounds__(256) void rvq_update(const float* __restrict__ res_in,
                                                  float* __restrict__ res_out,
                                                  const float* __restrict__ x,
                                                  const float* __restrict__ cbk,  // (M,D)
                                                  unsigned long long* __restrict__ keys,
                                                  float* __restrict__ idx_out,
                                                  int last) {
#pragma clang fp contract(off)
    __shared__ unsigned long long sk[4];
    const int tid = threadIdx.x;
    const int e = blockIdx.x * 256 + tid;
    const int p0 = blockIdx.x * 4;
    if (tid < 4) {
        unsigned long long k = keys[p0 + tid];
        sk[tid] = k;
        keys[p0 + tid] = ~0ULL;                       // reset for next step
        idx_out[p0 + tid] = (float)(unsigned int)k;   // exact for m < 2^24
    }
    __syncthreads();
    const int pi = tid >> 6;
    const int d = tid & 63;
    const int m = (int)(unsigned int)sk[pi];
    const float r = res_in[e] - cbk[(size_t)m * DD + d];  // exact fp32 sub
    if (last) res_out[e] = x[e] - r;   // quant = fl(x - fl(res - cb)); alias-safe
    else      res_out[e] = r;
}

extern "C" void kernel_launch(void* const* d_in, const int* in_sizes, int n_in,
                              void* d_out, int out_size, void* d_ws, size_t ws_size,
                              hipStream_t stream) {
    const float* x  = (const float*)d_in[0];
    const float* cb = (const float*)d_in[1];

    float* out = (float*)d_out;
    float* quant = out;                 // QSIZE floats
    float* idx_out = out + QSIZE;       // K*NPTS floats (indices as float)

    float* c2   = (float*)d_ws;                       // K*M floats (64 KB)
    float* res1 = c2 + (size_t)KK * MM;               // NPTS*D floats (8 MB)
    unsigned long long* keys =
        (unsigned long long*)(res1 + (size_t)QSIZE);  // NPTS u64 (256 KB)
    float* R[2] = { quant, res1 };                    // ping-pong residual

    rvq_prep<<<(KK * MM) / 256, 256, 0, stream>>>(cb, c2, keys);

    for (int k = 0; k < KK; ++k) {
        const float* rin = (k == 0) ? x : R[(k - 1) & 1];
        const int last = (k == KK - 1);
        float* rout = last ? quant : R[k & 1];
        rvq_main<<<(NPTS / PPB) * NCHUNK, PPB, 0, stream>>>(
            rin,
            cb + (size_t)k * MM * DD,
            c2 + (size_t)k * MM,
            keys);
        rvq_update<<<QSIZE / 256, 256, 0, stream>>>(
            rin, rout, x,
            cb + (size_t)k * MM * DD,
            keys,
            idx_out + (size_t)k * NPTS,
            last);
    }
}